// Round 8
// baseline (242.213 us; speedup 1.0000x reference)
//
#include <hip/hip_runtime.h>
#include <hip/hip_bf16.h>

#define TEMP_INV 14.285714285714286f  // 1/0.07
#define FSCALE 16.0f                  // fp8 pre-scale per operand
#define T1S (TEMP_INV / 256.0f)       // acc = 256*sim -> (sim-1)/T = acc*T1S - TEMP_INV

typedef __attribute__((ext_vector_type(4))) float f32x4;
typedef __attribute__((ext_vector_type(2))) long lx2;

#define ASYNC_COPY16(gp, lp)                                                  \
  __builtin_amdgcn_global_load_lds(                                          \
      (__attribute__((address_space(1))) const void*)(gp),                    \
      (__attribute__((address_space(3))) void*)(lp), 16, 0, 0)

// ---- row L2-normalize -> fp8 e4m3 (x16) in QUAD-MAJOR layout ----
// Within each 128-B k-block, byte for (s,quad,j) lives at quad*32 + s*8 + j
// (s = 32-elem MFMA k-step 0..3, quad = lane>>4, j = 0..7). This makes each
// lane's fragment for an s-PAIR one contiguous 16 B -> ds_read_b128.
// Lane l produces global k = 8l..8l+7: q=l&3, s=(l>>2)&3, block=l>>4.
__global__ __launch_bounds__(256) void norm_label_k(const float* __restrict__ feat,
                                                    uchar* __restrict__ fq,
                                                    const int* __restrict__ labels,
                                                    const int* __restrict__ kptr,
                                                    int* __restrict__ glab,
                                                    int* __restrict__ cnt,
                                                    float* __restrict__ gacc,
                                                    int* __restrict__ dcnt,
                                                    int N, int D) {
  const int row = (blockIdx.x * 256 + threadIdx.x) >> 6;
  const int lane = threadIdx.x & 63;
  if (row < N) {
    const float4* fr = (const float4*)(feat + (size_t)row * D);
    float4 v0 = fr[lane * 2];
    float4 v1 = fr[lane * 2 + 1];
    float ss = v0.x * v0.x + v0.y * v0.y + v0.z * v0.z + v0.w * v0.w +
               v1.x * v1.x + v1.y * v1.y + v1.z * v1.z + v1.w * v1.w;
    #pragma unroll
    for (int off = 32; off; off >>= 1) ss += __shfl_xor(ss, off, 64);
    const float inv = FSCALE / fmaxf(sqrtf(ss), 1e-12f);
    int w0 = 0, w1 = 0;
    w0 = __builtin_amdgcn_cvt_pk_fp8_f32(v0.x * inv, v0.y * inv, w0, false);
    w0 = __builtin_amdgcn_cvt_pk_fp8_f32(v0.z * inv, v0.w * inv, w0, true);
    w1 = __builtin_amdgcn_cvt_pk_fp8_f32(v1.x * inv, v1.y * inv, w1, false);
    w1 = __builtin_amdgcn_cvt_pk_fp8_f32(v1.z * inv, v1.w * inv, w1, true);
    uint2 o; o.x = (uint)w0; o.y = (uint)w1;
    // quad-major byte offset for this lane's 8 bytes
    const int pofs = (lane >> 4) * 128 + (lane & 3) * 32 + ((lane >> 2) & 3) * 8;
    *(uint2*)(fq + (size_t)row * D + pofs) = o;
  }
  if (blockIdx.x == 0) {
    const int k = *kptr;
    const int B = N / k;
    __shared__ int h[64];
    const int t = threadIdx.x;
    if (t < 2) gacc[t] = 0.f;
    if (t == 2) *dcnt = 0;
    if (t < 64) h[t] = 0;
    __syncthreads();
    for (int b = t; b < B; b += 256) {
      int lb = labels[(size_t)b * k];
      if (lb >= 0 && lb < 64) atomicAdd(&h[lb], 1);
    }
    __syncthreads();
    if (t < 64) cnt[t] = h[t];
    for (int i = t; i < N; i += 256) glab[i] = labels[(size_t)(i / k) * k];
  }
}

// ---- fused fp8 GEMM + masked-softmax-stats, upper-triangle blocks only ----
// 128x128 tile, BK=128 fp8 bytes, 4 waves, 4x4 frags of 16x16x32 fp8 MFMA.
// fq is quad-major so frag reads are ds_read_b128 (one per s-PAIR) with the
// conflict-free chunk^(row&7) swizzle geometry of round 6. 5 blocks/CU.
__global__ __launch_bounds__(256, 5) void gemm_k(const uchar* __restrict__ fq,
                                                 const int* __restrict__ glab,
                                                 float* __restrict__ part,
                                                 int N, int D) {
  __shared__ uchar As[128 * 128];
  __shared__ uchar Bs[128 * 128];
  const int t = threadIdx.x;
  const int lane = t & 63;
  const int wid = t >> 6;
  const int wrow = wid >> 1, wcol = wid & 1;
  const int quad = lane >> 4, l15 = lane & 15;

  // XCD-band remap: give each XCD a contiguous band of the triangle
  const int nb = N / 128;
  const int total = nb * (nb + 1) / 2;
  int gidx = blockIdx.x;
  if ((total & 7) == 0) {
    const int per = total >> 3;
    gidx = (blockIdx.x & 7) * per + (blockIdx.x >> 3);
  }
  // decode upper-triangle block (bi, bj), bj >= bi
  int idx = gidx, bi = 0;
  while (idx >= nb - bi) { idx -= nb - bi; bi++; }
  const int bj = bi + idx;
  const int i0 = bi * 128, j0 = bj * 128;
  const bool diagblk = (bi == bj);

  f32x4 acc[4][4];
  #pragma unroll
  for (int mi = 0; mi < 4; mi++)
    #pragma unroll
    for (int ni = 0; ni < 4; ni++) {
      f32x4 z = {0.f, 0.f, 0.f, 0.f};
      acc[mi][ni] = z;
    }

  // staging: wave w stages 64 rows (8 DMAs x 8 rows x 128 B) of A or B
  uchar* sb = (wid < 2) ? As : Bs;
  const int rbase = (wid & 1) * 64;
  const int rowstart = ((wid < 2) ? i0 : j0) + rbase;
  const int lrow = lane >> 3;  // 0..7: row within one 8-row DMA group
  const int lch = lane & 7;    // 16B LDS chunk written by this lane

  for (int kb = 0; kb < D; kb += 128) {  // 4 iterations (D=512 bytes)
    __syncthreads();
    #pragma unroll
    for (int i = 0; i < 8; i++) {
      const int rl = 8 * i + lrow;
      const int cg = lch ^ (rl & 7);  // swizzled source chunk
      ASYNC_COPY16(fq + (size_t)(rowstart + rl) * D + kb + cg * 16,
                   sb + (rbase + 8 * i) * 128);
    }
    __syncthreads();
    #pragma unroll
    for (int t2 = 0; t2 < 2; t2++) {   // s-pair index
      lx2 a2[4], b2[4];
      #pragma unroll
      for (int mi = 0; mi < 4; mi++) {
        const int r = wrow * 64 + mi * 16 + l15;
        a2[mi] = *(const lx2*)&As[r * 128 + (((2 * quad + t2) ^ (r & 7)) << 4)];
      }
      #pragma unroll
      for (int ni = 0; ni < 4; ni++) {
        const int r = wcol * 64 + ni * 16 + l15;
        b2[ni] = *(const lx2*)&Bs[r * 128 + (((2 * quad + t2) ^ (r & 7)) << 4)];
      }
      #pragma unroll
      for (int mi = 0; mi < 4; mi++)
        #pragma unroll
        for (int ni = 0; ni < 4; ni++) {
          acc[mi][ni] = __builtin_amdgcn_mfma_f32_16x16x32_fp8_fp8(a2[mi][0], b2[ni][0], acc[mi][ni], 0, 0, 0);
          acc[mi][ni] = __builtin_amdgcn_mfma_f32_16x16x32_fp8_fp8(a2[mi][1], b2[ni][1], acc[mi][ni], 0, 0, 0);
        }
    }
  }

  // ---- epilogue: stats into reused LDS, then one coalesced store ----
  __syncthreads();                 // all tile reads done; As reusable
  float* sf = (float*)As;          // [0:256) rowS(2x128) [256:512) rowP
                                   // [512:768) colS(2x128) [768:1024) colP
  const int colbase = j0 + wcol * 64 + l15;
  int clab[4];
  #pragma unroll
  for (int ni = 0; ni < 4; ni++) clab[ni] = glab[colbase + ni * 16];

  float colE[4] = {0.f, 0.f, 0.f, 0.f};
  float colP[4] = {0.f, 0.f, 0.f, 0.f};

  #pragma unroll
  for (int mi = 0; mi < 4; mi++) {
    const int lrw = wrow * 64 + mi * 16 + quad * 4;
    #pragma unroll
    for (int r = 0; r < 4; r++) {
      const int row = i0 + lrw + r;
      const int rlab = glab[row];
      float Ssum = 0.f, Psum = 0.f;
      #pragma unroll
      for (int ni = 0; ni < 4; ni++) {
        const int col = colbase + ni * 16;
        const float val = acc[mi][ni][r];
        const float lg = fmaf(val, T1S, -TEMP_INV);  // (sim - 1)/T
        const bool diag = diagblk && (row == col);
        const float e = diag ? 0.f : __expf(lg);
        const float pm = (!diag && rlab == clab[ni]) ? lg : 0.f;
        Ssum += e; Psum += pm;
        colE[ni] += e; colP[ni] += pm;
      }
      #pragma unroll
      for (int off = 8; off; off >>= 1) {
        Ssum += __shfl_xor(Ssum, off, 64);
        Psum += __shfl_xor(Psum, off, 64);
      }
      if (l15 == 0) {
        sf[wcol * 128 + lrw + r]       = Ssum;
        sf[256 + wcol * 128 + lrw + r] = Psum;
      }
    }
  }
  if (!diagblk) {
    #pragma unroll
    for (int ni = 0; ni < 4; ni++) {
      float e = colE[ni];
      float p = colP[ni];
      e += __shfl_xor(e, 16, 64);
      e += __shfl_xor(e, 32, 64);
      p += __shfl_xor(p, 16, 64);
      p += __shfl_xor(p, 32, 64);
      const int lcol = wcol * 64 + ni * 16 + l15;
      if (quad == 0) {
        sf[512 + wrow * 128 + lcol] = e;
        sf[768 + wrow * 128 + lcol] = p;
      }
    }
  }
  __syncthreads();
  float* dst = part + (size_t)gidx * 512;
  if (t < 128) {
    dst[t]       = sf[t] + sf[128 + t];          // rowS
    dst[128 + t] = sf[256 + t] + sf[384 + t];    // rowP
  } else if (!diagblk) {
    const int u = t - 128;
    dst[256 + u] = sf[512 + u] + sf[640 + u];    // colS
    dst[384 + u] = sf[768 + u] + sf[896 + u];    // colP
  }
}

// ---- gather partials -> per-row loss -> global reduce -> finalize ----
__global__ __launch_bounds__(128) void reduce_loss_k(const float* __restrict__ part,
                                                     const int* __restrict__ glab,
                                                     const int* __restrict__ cnt,
                                                     const int* __restrict__ kptr,
                                                     float* __restrict__ gacc,
                                                     int* __restrict__ dcnt,
                                                     float* __restrict__ out, int N) {
  const int nb = N / 128;
  const int b = blockIdx.x;
  const int t = threadIdx.x;
  const int i = b * 128 + t;
  float S = 0.f, P = 0.f;
  const int base = b * nb - b * (b - 1) / 2;
  for (int bj = b; bj < nb; bj++) {          // row-side partials
    const float* p = part + (size_t)(base + bj - b) * 512;
    S += p[t];
    P += p[128 + t];
  }
  for (int bi = 0; bi < b; bi++) {           // col-side partials (symmetry)
    const int idx = bi * nb - bi * (bi - 1) / 2 + (b - bi);
    const float* p = part + (size_t)idx * 512;
    S += p[256 + t];
    P += p[384 + t];
  }
  const int k = *kptr;
  const int np = cnt[glab[i]] * k - 1;
  float l = 0.f, v = 0.f;
  if (np > 0) {
    l = -(P - (float)np * logf(S + 1e-8f)) / (float)np;
    v = 1.f;
  }
  #pragma unroll
  for (int off = 32; off; off >>= 1) {
    l += __shfl_xor(l, off, 64);
    v += __shfl_xor(v, off, 64);
  }
  __shared__ float sl[2], sv[2];
  if ((t & 63) == 0) { sl[t >> 6] = l; sv[t >> 6] = v; }
  __syncthreads();
  if (t == 0) {
    atomicAdd(&gacc[0], sl[0] + sl[1]);
    atomicAdd(&gacc[1], sv[0] + sv[1]);
    __threadfence();
    const int prev = atomicAdd(dcnt, 1);
    if (prev == (int)gridDim.x - 1) {
      const float L = atomicAdd(&gacc[0], 0.f);
      const float V = atomicAdd(&gacc[1], 0.f);
      out[0] = L / fmaxf(V, 1.f);
    }
  }
}

extern "C" void kernel_launch(void* const* d_in, const int* in_sizes, int n_in,
                              void* d_out, int out_size, void* d_ws, size_t ws_size,
                              hipStream_t stream) {
  const float* feat = (const float*)d_in[0];
  const int* labels = (const int*)d_in[1];
  const int* kptr   = (const int*)d_in[2];
  const int N = in_sizes[1];
  const int D = in_sizes[0] / N;  // 512

  const int nb = N / 128;
  const int total = nb * (nb + 1) / 2;

  char* ws = (char*)d_ws;
  uchar* fq = (uchar*)ws;
  size_t off = (size_t)N * D;  // fp8: 1 byte/elem
  float* part = (float*)(ws + off); off += (size_t)total * 512 * sizeof(float);
  int* glab   = (int*)(ws + off);   off += (size_t)N * sizeof(int);
  int* cnt    = (int*)(ws + off);   off += 64 * sizeof(int);
  float* gacc = (float*)(ws + off); off += 2 * sizeof(float);
  int* dcnt   = (int*)(ws + off);   off += sizeof(int);

  norm_label_k<<<(N + 3) / 4, 256, 0, stream>>>(feat, fq, labels, kptr, glab, cnt,
                                                gacc, dcnt, N, D);
  gemm_k<<<total, 256, 0, stream>>>(fq, glab, part, N, D);
  reduce_loss_k<<<nb, 128, 0, stream>>>(part, glab, cnt, kptr, gacc, dcnt,
                                        (float*)d_out, N);
}

// Round 9
// 158.573 us; speedup vs baseline: 1.5274x; 1.5274x over previous
//
#include <hip/hip_runtime.h>
#include <hip/hip_bf16.h>

#define TEMP_INV 14.285714285714286f  // 1/0.07
#define FSCALE 16.0f                  // fp8 pre-scale per operand
#define T1S (TEMP_INV / 256.0f)       // acc = 256*sim -> (sim-1)/T = acc*T1S - TEMP_INV

typedef __attribute__((ext_vector_type(4))) float f32x4;
typedef __attribute__((ext_vector_type(2))) long lx2;

#define ASYNC_COPY16(gp, lp)                                                  \
  __builtin_amdgcn_global_load_lds(                                          \
      (__attribute__((address_space(1))) const void*)(gp),                    \
      (__attribute__((address_space(3))) void*)(lp), 16, 0, 0)

// ---- row L2-normalize -> fp8 e4m3 (x16) in QUAD-MAJOR layout ----
// Within each 128-B k-block, byte for (s,quad,j) lives at quad*32 + s*8 + j,
// so a lane's fragment for an s-PAIR is one contiguous 16 B -> ds_read_b128.
__global__ __launch_bounds__(256) void norm_label_k(const float* __restrict__ feat,
                                                    uchar* __restrict__ fq,
                                                    const int* __restrict__ labels,
                                                    const int* __restrict__ kptr,
                                                    int* __restrict__ glab,
                                                    int* __restrict__ cnt,
                                                    float* __restrict__ gacc,
                                                    int* __restrict__ dcnt,
                                                    int N, int D) {
  const int row = (blockIdx.x * 256 + threadIdx.x) >> 6;
  const int lane = threadIdx.x & 63;
  if (row < N) {
    const float4* fr = (const float4*)(feat + (size_t)row * D);
    float4 v0 = fr[lane * 2];
    float4 v1 = fr[lane * 2 + 1];
    float ss = v0.x * v0.x + v0.y * v0.y + v0.z * v0.z + v0.w * v0.w +
               v1.x * v1.x + v1.y * v1.y + v1.z * v1.z + v1.w * v1.w;
    #pragma unroll
    for (int off = 32; off; off >>= 1) ss += __shfl_xor(ss, off, 64);
    const float inv = FSCALE / fmaxf(sqrtf(ss), 1e-12f);
    int w0 = 0, w1 = 0;
    w0 = __builtin_amdgcn_cvt_pk_fp8_f32(v0.x * inv, v0.y * inv, w0, false);
    w0 = __builtin_amdgcn_cvt_pk_fp8_f32(v0.z * inv, v0.w * inv, w0, true);
    w1 = __builtin_amdgcn_cvt_pk_fp8_f32(v1.x * inv, v1.y * inv, w1, false);
    w1 = __builtin_amdgcn_cvt_pk_fp8_f32(v1.z * inv, v1.w * inv, w1, true);
    uint2 o; o.x = (uint)w0; o.y = (uint)w1;
    const int pofs = (lane >> 4) * 128 + (lane & 3) * 32 + ((lane >> 2) & 3) * 8;
    *(uint2*)(fq + (size_t)row * D + pofs) = o;
  }
  if (blockIdx.x == 0) {
    const int k = *kptr;
    const int B = N / k;
    __shared__ int h[64];
    const int t = threadIdx.x;
    if (t < 2) gacc[t] = 0.f;
    if (t == 2) *dcnt = 0;
    if (t < 64) h[t] = 0;
    __syncthreads();
    for (int b = t; b < B; b += 256) {
      int lb = labels[(size_t)b * k];
      if (lb >= 0 && lb < 64) atomicAdd(&h[lb], 1);
    }
    __syncthreads();
    if (t < 64) cnt[t] = h[t];
    for (int i = t; i < N; i += 256) glab[i] = labels[(size_t)(i / k) * k];
  }
}

// ---- fused fp8 GEMM + masked-softmax-stats, upper-triangle 256x256 tiles ----
// 1024 thr / 16 waves (4x4 grid, 64x64 per wave), BK=128 fp8 bytes, LDS 64 KB.
// Staged traffic: 528 blocks x 256 KB = 135 MB (2x less than 128^2 tiling).
// launch_bounds(1024,4): combined budget 128 = 64 VGPR + 64 AGPR (r7-proven).
__global__ __launch_bounds__(1024, 4) void gemm_k(const uchar* __restrict__ fq,
                                                  const int* __restrict__ glab,
                                                  float* __restrict__ part,
                                                  int N, int D) {
  __shared__ uchar As[256 * 128];
  __shared__ uchar Bs[256 * 128];
  const int t = threadIdx.x;
  const int lane = t & 63;
  const int wid = t >> 6;                 // 0..15
  const int wrow = wid >> 2, wcol = wid & 3;
  const int quad = lane >> 4, l15 = lane & 15;

  // XCD-band remap (528 % 8 == 0 -> per-XCD contiguous bands)
  const int nb = N / 256;
  const int total = nb * (nb + 1) / 2;
  int gidx = blockIdx.x;
  if ((total & 7) == 0) {
    const int per = total >> 3;
    gidx = (blockIdx.x & 7) * per + (blockIdx.x >> 3);
  }
  int idx = gidx, bi = 0;
  while (idx >= nb - bi) { idx -= nb - bi; bi++; }
  const int bj = bi + idx;
  const int i0 = bi * 256, j0 = bj * 256;
  const bool diagblk = (bi == bj);

  f32x4 acc[4][4];
  #pragma unroll
  for (int mi = 0; mi < 4; mi++)
    #pragma unroll
    for (int ni = 0; ni < 4; ni++) {
      f32x4 z = {0.f, 0.f, 0.f, 0.f};
      acc[mi][ni] = z;
    }

  // staging: waves 0..7 stage A (32 rows each), 8..15 stage B
  const bool stA = wid < 8;
  uchar* sb = stA ? As : Bs;
  const int rbase = (wid & 7) * 32;
  const int rowstart = (stA ? i0 : j0) + rbase;
  const int lrow = lane >> 3;  // 0..7
  const int lch = lane & 7;

  for (int kb = 0; kb < D; kb += 128) {  // 4 iterations (D = 512 bytes)
    __syncthreads();
    #pragma unroll
    for (int g = 0; g < 4; g++) {
      const int cg = lch ^ lrow;  // (rl & 7) == lrow
      ASYNC_COPY16(fq + (size_t)(rowstart + g * 8 + lrow) * D + kb + cg * 16,
                   sb + (rbase + g * 8) * 128);
    }
    __syncthreads();
    #pragma unroll
    for (int t2 = 0; t2 < 2; t2++) {
      lx2 a2[4], b2[4];
      #pragma unroll
      for (int mi = 0; mi < 4; mi++) {
        const int r = wrow * 64 + mi * 16 + l15;
        a2[mi] = *(const lx2*)&As[r * 128 + (((2 * quad + t2) ^ (r & 7)) << 4)];
      }
      #pragma unroll
      for (int ni = 0; ni < 4; ni++) {
        const int r = wcol * 64 + ni * 16 + l15;
        b2[ni] = *(const lx2*)&Bs[r * 128 + (((2 * quad + t2) ^ (r & 7)) << 4)];
      }
      #pragma unroll
      for (int mi = 0; mi < 4; mi++)
        #pragma unroll
        for (int ni = 0; ni < 4; ni++) {
          acc[mi][ni] = __builtin_amdgcn_mfma_f32_16x16x32_fp8_fp8(a2[mi][0], b2[ni][0], acc[mi][ni], 0, 0, 0);
          acc[mi][ni] = __builtin_amdgcn_mfma_f32_16x16x32_fp8_fp8(a2[mi][1], b2[ni][1], acc[mi][ni], 0, 0, 0);
        }
    }
  }

  // ---- epilogue: stats into reused LDS (As), one coalesced 4 KB record ----
  __syncthreads();
  float* sf = (float*)As;  // [0:1024) rowS[wcol][256]  [1024:2048) rowP
                           // [2048:3072) colS[wrow][256]  [3072:4096) colP
  const int colbase = j0 + wcol * 64 + l15;
  int clab[4];
  #pragma unroll
  for (int ni = 0; ni < 4; ni++) clab[ni] = glab[colbase + ni * 16];

  float colE[4] = {0.f, 0.f, 0.f, 0.f};
  float colP[4] = {0.f, 0.f, 0.f, 0.f};

  #pragma unroll
  for (int mi = 0; mi < 4; mi++) {
    const int lrw = wrow * 64 + mi * 16 + quad * 4;  // local row base
    #pragma unroll
    for (int r = 0; r < 4; r++) {
      const int row = i0 + lrw + r;
      const int rlab = glab[row];
      float Ssum = 0.f, Psum = 0.f;
      #pragma unroll
      for (int ni = 0; ni < 4; ni++) {
        const int col = colbase + ni * 16;
        const float val = acc[mi][ni][r];
        const float lg = fmaf(val, T1S, -TEMP_INV);  // (sim - 1)/T
        const bool diag = diagblk && (row == col);
        const float e = diag ? 0.f : __expf(lg);
        const float pm = (!diag && rlab == clab[ni]) ? lg : 0.f;
        Ssum += e; Psum += pm;
        colE[ni] += e; colP[ni] += pm;
      }
      #pragma unroll
      for (int off = 8; off; off >>= 1) {
        Ssum += __shfl_xor(Ssum, off, 64);
        Psum += __shfl_xor(Psum, off, 64);
      }
      if (l15 == 0) {
        sf[wcol * 256 + lrw + r]        = Ssum;
        sf[1024 + wcol * 256 + lrw + r] = Psum;
      }
    }
  }
  if (!diagblk) {
    #pragma unroll
    for (int ni = 0; ni < 4; ni++) {
      float e = colE[ni];
      float p = colP[ni];
      e += __shfl_xor(e, 16, 64);
      e += __shfl_xor(e, 32, 64);
      p += __shfl_xor(p, 16, 64);
      p += __shfl_xor(p, 32, 64);
      const int lc = wcol * 64 + ni * 16 + l15;
      if (quad == 0) {
        sf[2048 + wrow * 256 + lc] = e;
        sf[3072 + wrow * 256 + lc] = p;
      }
    }
  }
  __syncthreads();
  float* dst = part + (size_t)gidx * 1024;
  if (t < 256) {
    dst[t]       = sf[t] + sf[256 + t] + sf[512 + t] + sf[768 + t];
    dst[256 + t] = sf[1024 + t] + sf[1280 + t] + sf[1536 + t] + sf[1792 + t];
  } else if (t < 512 && !diagblk) {
    const int u = t - 256;
    dst[512 + u] = sf[2048 + u] + sf[2304 + u] + sf[2560 + u] + sf[2816 + u];
    dst[768 + u] = sf[3072 + u] + sf[3328 + u] + sf[3584 + u] + sf[3840 + u];
  }
}

// ---- gather partials -> per-row loss -> global reduce -> finalize ----
__global__ __launch_bounds__(256) void reduce_loss_k(const float* __restrict__ part,
                                                     const int* __restrict__ glab,
                                                     const int* __restrict__ cnt,
                                                     const int* __restrict__ kptr,
                                                     float* __restrict__ gacc,
                                                     int* __restrict__ dcnt,
                                                     float* __restrict__ out, int N) {
  const int nb = N / 256;
  const int b = blockIdx.x;
  const int t = threadIdx.x;
  const int i = b * 256 + t;
  float S = 0.f, P = 0.f;
  const int base = b * nb - b * (b - 1) / 2;
  for (int bj = b; bj < nb; bj++) {          // row-side partials
    const float* p = part + (size_t)(base + bj - b) * 1024;
    S += p[t];
    P += p[256 + t];
  }
  for (int bi = 0; bi < b; bi++) {           // col-side partials (symmetry)
    const int idx = bi * nb - bi * (bi - 1) / 2 + (b - bi);
    const float* p = part + (size_t)idx * 1024;
    S += p[512 + t];
    P += p[768 + t];
  }
  const int k = *kptr;
  const int np = cnt[glab[i]] * k - 1;
  float l = 0.f, v = 0.f;
  if (np > 0) {
    l = -(P - (float)np * logf(S + 1e-8f)) / (float)np;
    v = 1.f;
  }
  #pragma unroll
  for (int off = 32; off; off >>= 1) {
    l += __shfl_xor(l, off, 64);
    v += __shfl_xor(v, off, 64);
  }
  __shared__ float sl[4], sv[4];
  if ((t & 63) == 0) { sl[t >> 6] = l; sv[t >> 6] = v; }
  __syncthreads();
  if (t == 0) {
    atomicAdd(&gacc[0], sl[0] + sl[1] + sl[2] + sl[3]);
    atomicAdd(&gacc[1], sv[0] + sv[1] + sv[2] + sv[3]);
    __threadfence();
    const int prev = atomicAdd(dcnt, 1);
    if (prev == (int)gridDim.x - 1) {
      const float L = atomicAdd(&gacc[0], 0.f);
      const float V = atomicAdd(&gacc[1], 0.f);
      out[0] = L / fmaxf(V, 1.f);
    }
  }
}

extern "C" void kernel_launch(void* const* d_in, const int* in_sizes, int n_in,
                              void* d_out, int out_size, void* d_ws, size_t ws_size,
                              hipStream_t stream) {
  const float* feat = (const float*)d_in[0];
  const int* labels = (const int*)d_in[1];
  const int* kptr   = (const int*)d_in[2];
  const int N = in_sizes[1];
  const int D = in_sizes[0] / N;  // 512

  const int nb = N / 256;
  const int total = nb * (nb + 1) / 2;

  char* ws = (char*)d_ws;
  uchar* fq = (uchar*)ws;
  size_t off = (size_t)N * D;  // fp8: 1 byte/elem
  float* part = (float*)(ws + off); off += (size_t)total * 1024 * sizeof(float);
  int* glab   = (int*)(ws + off);   off += (size_t)N * sizeof(int);
  int* cnt    = (int*)(ws + off);   off += 64 * sizeof(int);
  float* gacc = (float*)(ws + off); off += 2 * sizeof(float);
  int* dcnt   = (int*)(ws + off);   off += sizeof(int);

  norm_label_k<<<(N + 3) / 4, 256, 0, stream>>>(feat, fq, labels, kptr, glab, cnt,
                                                gacc, dcnt, N, D);
  gemm_k<<<total, 1024, 0, stream>>>(fq, glab, part, N, D);
  reduce_loss_k<<<nb, 256, 0, stream>>>(part, glab, cnt, kptr, gacc, dcnt,
                                        (float*)d_out, N);
}